// Round 11
// baseline (32.342 us; speedup 1.0000x reference)
//
#include <hip/hip_runtime.h>
#include <math.h>

#define BB 4
#define TQ 256
#define TV 256
#define DD 512
#define UU 128
#define NEGV (-1e9f)

__device__ __forceinline__ float fast_rcp(float x) {
    return __builtin_amdgcn_rcpf(x);   // v_rcp_f32
}

// ---------------- kernel 1: projections -> Eq=exp(2q), Ek=exp(2k) (transposed) ----------------
// (proven R5 body, unchanged) 512 blocks x 512 thr; 0..255 q-proj, 256..511 k-proj.
__global__ __launch_bounds__(512, 4) void proj_kernel(
    const float* __restrict__ query, const float* __restrict__ value,
    const float* __restrict__ W1, const float* __restrict__ W2,
    float* __restrict__ eqp /* [B*TQ][U] = exp(2q) */,
    float* __restrict__ ekT /* [B][U][TV] = exp(2k) */) {
    int bid = blockIdx.x;
    int which = bid >> 8;              // 0 = q, 1 = k
    int row0 = (bid & 255) * 4;
    const float* X = which ? value : query;
    const float* W = which ? W2 : W1;

    __shared__ float xs[4 * DD];       // 8 KB: 4 input rows
    __shared__ float cmb[3][4][UU];    // 6 KB: split-K partials
    int tid = threadIdx.x;
    ((float4*)xs)[tid] = ((const float4*)(X + (size_t)row0 * DD))[tid];
    __syncthreads();

    int kc = tid >> 7;                 // K-quarter 0..3
    int u = tid & 127;
    const float* Wp = W + (size_t)(kc * (DD / 4)) * UU + u;
    const float* x0 = xs + kc * (DD / 4);
    float a0 = 0.f, a1 = 0.f, a2 = 0.f, a3 = 0.f;
    #pragma unroll 8
    for (int d = 0; d < DD / 4; ++d) {
        float w = Wp[(size_t)d * UU];          // coalesced across u
        a0 = fmaf(x0[d], w, a0);               // LDS broadcast
        a1 = fmaf(x0[DD + d], w, a1);
        a2 = fmaf(x0[2 * DD + d], w, a2);
        a3 = fmaf(x0[3 * DD + d], w, a3);
    }
    if (kc) {
        cmb[kc - 1][0][u] = a0; cmb[kc - 1][1][u] = a1;
        cmb[kc - 1][2][u] = a2; cmb[kc - 1][3][u] = a3;
    }
    __syncthreads();
    if (!kc) {
        a0 = __expf(2.f * (((a0 + cmb[0][0][u]) + cmb[1][0][u]) + cmb[2][0][u]));
        a1 = __expf(2.f * (((a1 + cmb[0][1][u]) + cmb[1][1][u]) + cmb[2][1][u]));
        a2 = __expf(2.f * (((a2 + cmb[0][2][u]) + cmb[1][2][u]) + cmb[2][2][u]));
        a3 = __expf(2.f * (((a3 + cmb[0][3][u]) + cmb[1][3][u]) + cmb[2][3][u]));
        if (which == 0) {
            float* p = eqp + (size_t)row0 * UU + u;
            p[0 * UU] = a0; p[1 * UU] = a1; p[2 * UU] = a2; p[3 * UU] = a3;
        } else {
            int b = row0 >> 8, v0 = row0 & 255;
            float* p = ekT + ((size_t)b * UU + u) * TV + v0;
            p[0] = a0; p[1] = a1; p[2] = a2; p[3] = a3;
        }
    }
}

// ---------------- kernel 2: FUSED scores + masked softmax + context ----------------
// 512 blocks x 512 thr; block = 2 q-rows -> 2 blocks/CU co-resident (latency overlap).
// Phase A: s'[r,v] = -2 * sum_u sc_u * rcp(1 + Eq[r,u]*Ek[u,v]) (shift-invariant),
//          u-split-4; masked softmax; weights -> LDS + d_out.
// Phase B: context = weights(LDS) @ value, float4 loads, v-split-4 combined in LDS.
__global__ __launch_bounds__(512, 4) void attn_kernel(
    const float* __restrict__ eqp, const float* __restrict__ ekT,
    const float* __restrict__ scale, const unsigned char* __restrict__ m,
    const float* __restrict__ value,
    float* __restrict__ ctx, float* __restrict__ weights) {
    int blk = blockIdx.x;              // 0..511
    int b = blk >> 7;
    int q0 = (blk & 127) * 2;
    int tid = threadIdx.x;             // 0..511

    __shared__ float eq2[2][UU];       // 1 KB
    __shared__ float sc2[UU];          // 512 B: -2*scale
    __shared__ float pb[3][2][TV];     // 6 KB: phase-A partials (h=1..3)
    __shared__ float4 part4[3][2][128];// 12 KB: phase-B partials (vh=1..3)
    __shared__ float sv[2][TV];        // 2 KB: scores, then weights
    __shared__ float redM[2][4], redS[2][4];
    __shared__ int flagF, flagB;

    if (tid == 0) { flagF = 0; flagB = 0; }
    if (tid < 2 * UU) eq2[tid >> 7][tid & 127] = eqp[(size_t)(b * TQ + q0) * UU + tid];
    else if (tid < 3 * UU) sc2[tid - 2 * UU] = -2.f * scale[tid - 2 * UU];
    if (tid < 256) {                   // mask layout probe, first 1024 B safe
        uchar4 c4 = ((const uchar4*)m)[tid];
        if (c4.w == 0x3f) flagF = 1;                 // float32 1.0f tail byte
        if (c4.y | c4.z | c4.w) flagB = 1;           // off-word nonzero -> u8
    }
    __syncthreads();

    // ---- phase A: scores, u-split-4 (32 u per group) ----
    {
        int vp = tid & 127;            // float2 v-pair
        int h = tid >> 7;              // u-quarter 0..3
        const float2* kb2 = (const float2*)(ekT + ((size_t)b * UU + h * 32) * TV) + vp;
        const float* eqh0 = &eq2[0][h * 32];
        const float* eqh1 = &eq2[1][h * 32];
        const float* sch = &sc2[h * 32];
        float ax0 = 0.f, ay0 = 0.f, ax1 = 0.f, ay1 = 0.f;
        #pragma unroll
        for (int i = 0; i < 32; ++i) {
            float2 ek = kb2[(size_t)i * (TV / 2)];   // 8B, coalesced across vp
            float w2 = sch[i];
            float e0 = eqh0[i], e1 = eqh1[i];
            ax0 = fmaf(w2, fast_rcp(fmaf(e0, ek.x, 1.f)), ax0);
            ay0 = fmaf(w2, fast_rcp(fmaf(e0, ek.y, 1.f)), ay0);
            ax1 = fmaf(w2, fast_rcp(fmaf(e1, ek.x, 1.f)), ax1);
            ay1 = fmaf(w2, fast_rcp(fmaf(e1, ek.y, 1.f)), ay1);
        }
        if (h > 0) {
            pb[h - 1][0][2 * vp] = ax0; pb[h - 1][0][2 * vp + 1] = ay0;
            pb[h - 1][1][2 * vp] = ax1; pb[h - 1][1][2 * vp + 1] = ay1;
        }
        __syncthreads();
        if (h == 0) {
            float rx0 = ax0, ry0 = ay0, rx1 = ax1, ry1 = ay1;
            #pragma unroll
            for (int j = 0; j < 3; ++j) {
                rx0 += pb[j][0][2 * vp]; ry0 += pb[j][0][2 * vp + 1];
                rx1 += pb[j][1][2 * vp]; ry1 += pb[j][1][2 * vp + 1];
            }
            sv[0][2 * vp] = rx0; sv[0][2 * vp + 1] = ry0;
            sv[1][2 * vp] = rx1; sv[1][2 * vp + 1] = ry1;
        }
        __syncthreads();
    }

    // ---- masked softmax: threads 0..255 own one v each ----
    {
        int v = tid & 255;
        float mk;
        {
            int idx = b * TV + v;
            bool ok;
            if (flagF)      ok = (m[4 * idx + 3] != 0);
            else if (flagB) ok = (m[idx] != 0);
            else            ok = (m[4 * idx] != 0);  // int32 LSB
            mk = ok ? __builtin_inff() : NEGV;
        }
        float s[2], e[2];
        #pragma unroll
        for (int r = 0; r < 2; ++r) s[r] = fminf(sv[r][v], mk);

        int wid = tid >> 6, lane = tid & 63;
        #pragma unroll
        for (int r = 0; r < 2; ++r) {
            float mm = s[r];
            #pragma unroll
            for (int off = 32; off >= 1; off >>= 1) mm = fmaxf(mm, __shfl_xor(mm, off));
            if (tid < 256 && lane == 0) redM[r][wid] = mm;
        }
        __syncthreads();
        #pragma unroll
        for (int r = 0; r < 2; ++r) {
            float mfull = fmaxf(fmaxf(redM[r][0], redM[r][1]),
                                fmaxf(redM[r][2], redM[r][3]));
            e[r] = __expf(s[r] - mfull);
            float t = e[r];
            #pragma unroll
            for (int off = 32; off >= 1; off >>= 1) t += __shfl_xor(t, off);
            if (tid < 256 && lane == 0) redS[r][wid] = t;
        }
        __syncthreads();
        if (tid < 256) {
            #pragma unroll
            for (int r = 0; r < 2; ++r) {
                float rs = fast_rcp((redS[r][0] + redS[r][1]) + (redS[r][2] + redS[r][3]));
                float wv = e[r] * rs;
                weights[(size_t)(b * TQ + q0 + r) * TV + v] = wv;
                sv[r][v] = wv;                       // weights for phase B
            }
        }
        __syncthreads();
    }

    // ---- phase B: context = weights(LDS) @ value, float4, v-split-4 ----
    {
        int df = tid & 127;            // float4 d-column (128 x 4 = 512 d)
        int vh = tid >> 7;             // v-quarter 0..3 (64 v each)
        const float4* vb = (const float4*)(value + ((size_t)b * TV + vh * 64) * DD) + df;
        const float* wr0 = &sv[0][vh * 64];
        const float* wr1 = &sv[1][vh * 64];
        float4 c0 = make_float4(0.f, 0.f, 0.f, 0.f);
        float4 c1 = make_float4(0.f, 0.f, 0.f, 0.f);
        #pragma unroll 16
        for (int t = 0; t < 64; ++t) {
            float4 vv = vb[(size_t)t * (DD / 4)];    // 16B, coalesced across df
            float w0 = wr0[t], w1 = wr1[t];
            c0.x = fmaf(w0, vv.x, c0.x); c0.y = fmaf(w0, vv.y, c0.y);
            c0.z = fmaf(w0, vv.z, c0.z); c0.w = fmaf(w0, vv.w, c0.w);
            c1.x = fmaf(w1, vv.x, c1.x); c1.y = fmaf(w1, vv.y, c1.y);
            c1.z = fmaf(w1, vv.z, c1.z); c1.w = fmaf(w1, vv.w, c1.w);
        }
        if (vh > 0) {
            part4[vh - 1][0][df] = c0;
            part4[vh - 1][1][df] = c1;
        }
        __syncthreads();
        if (vh == 0) {
            #pragma unroll
            for (int j = 0; j < 3; ++j) {
                float4 p0 = part4[j][0][df], p1 = part4[j][1][df];
                c0.x += p0.x; c0.y += p0.y; c0.z += p0.z; c0.w += p0.w;
                c1.x += p1.x; c1.y += p1.y; c1.z += p1.z; c1.w += p1.w;
            }
            ((float4*)(ctx + (size_t)(b * TQ + q0 + 0) * DD))[df] = c0;
            ((float4*)(ctx + (size_t)(b * TQ + q0 + 1) * DD))[df] = c1;
        }
    }
}

extern "C" void kernel_launch(void* const* d_in, const int* in_sizes, int n_in,
                              void* d_out, int out_size, void* d_ws, size_t ws_size,
                              hipStream_t stream) {
    const float* query = (const float*)d_in[0];
    const float* value = (const float*)d_in[1];
    const unsigned char* mask = (const unsigned char*)d_in[2];
    const float* W1 = (const float*)d_in[3];
    const float* W2 = (const float*)d_in[4];
    const float* scale = (const float*)d_in[5];

    float* ctx = (float*)d_out;                              // [B,TQ,D]
    float* weights = (float*)d_out + (size_t)BB * TQ * DD;   // [B,TQ,TV]

    float* eqp = (float*)d_ws;                               // 512 KB
    float* ekT = eqp + (size_t)BB * TQ * UU;                 // 512 KB

    proj_kernel<<<512, 512, 0, stream>>>(query, value, W1, W2, eqp, ekT);
    attn_kernel<<<512, 512, 0, stream>>>(eqp, ekT, scale, mask, value, ctx, weights);
}